// Round 3
// baseline (2497.753 us; speedup 1.0000x reference)
//
#include <hip/hip_runtime.h>
#include <cstdint>
#include <cstddef>

#define HID 512
#define BATCH 4096
#define T_STEPS 20
#define NSTEP (T_STEPS - 1)
#define GRID 512

typedef unsigned short ushort_t;
typedef __attribute__((ext_vector_type(8))) __bf16 bf16x8;
typedef __attribute__((ext_vector_type(4))) float f32x4;

typedef __attribute__((address_space(1))) void gvoid;
typedef __attribute__((address_space(3))) void lvoid;

// fp32 -> bf16 round-to-nearest-even (finite inputs only)
__device__ __forceinline__ unsigned short f2bf(float f) {
  unsigned int u = __float_as_uint(f);
  u += 0x7FFFu + ((u >> 16) & 1u);
  return (unsigned short)(u >> 16);
}

__device__ __forceinline__ float wave_max(float v) {
#pragma unroll
  for (int off = 32; off > 0; off >>= 1) v = fmaxf(v, __shfl_xor(v, off));
  return v;
}
__device__ __forceinline__ float wave_sum(float v) {
#pragma unroll
  for (int off = 32; off > 0; off >>= 1) v += __shfl_xor(v, off);
  return v;
}

// async global->LDS, 16B per lane; lds base must be wave-uniform (HW adds lane*16)
__device__ __forceinline__ void load_lds16(const void* g, void* l) {
  __builtin_amdgcn_global_load_lds((gvoid*)g, (lvoid*)l, 16, 0, 0);
}

// Device-scope grid barrier. All GRID blocks guaranteed co-resident:
// __launch_bounds__(256,2) -> >=2 waves/SIMD -> >=2 blocks/CU by VGPR;
// LDS 36864B -> 4 blocks/CU; 256 CUs * 2 = 512 = GRID.
// Release on arrival (flushes our L2 writes), relaxed spin (no L1-inv per
// poll), single acquire on exit (invalidates L1/L2 so we see remote writes).
__device__ __forceinline__ void grid_barrier(unsigned* cnt, unsigned target) {
  __syncthreads();
  if (threadIdx.x == 0) {
    __hip_atomic_fetch_add(cnt, 1u, __ATOMIC_RELEASE, __HIP_MEMORY_SCOPE_AGENT);
    while (__hip_atomic_load(cnt, __ATOMIC_RELAXED, __HIP_MEMORY_SCOPE_AGENT) < target)
      __builtin_amdgcn_s_sleep(16);
    volatile unsigned dummy =
        __hip_atomic_load(cnt, __ATOMIC_ACQUIRE, __HIP_MEMORY_SCOPE_AGENT);
    (void)dummy;
  }
  __syncthreads();
}

__global__ void zero_kernel(unsigned* c) {
  if (threadIdx.x == 0) *c = 0u;
}

__global__ __launch_bounds__(256, 2) void fused_kernel(
    const float* __restrict__ y, const float* __restrict__ ts,
    const float* __restrict__ Wi, const float* __restrict__ Wg,
    const float* __restrict__ Wo, const float* __restrict__ Wout,
    const float* __restrict__ bout, const float* __restrict__ Wfc,
    const float* __restrict__ bfc, float* __restrict__ out,
    float* __restrict__ z, ushort_t* __restrict__ zb,
    ushort_t* __restrict__ dh, ushort_t* __restrict__ Wcat2,
    ushort_t* __restrict__ WoutB, unsigned* __restrict__ cnt) {
  // LDS union: phase A: As 8192B + Bs 6144B. phase B: Bs 32768 + As 2048 +
  // redm 512 + redA 512 + redB 512 = 36352.
  __shared__ __align__(16) char smem[36864];

  const int tid = threadIdx.x;
  const int wave = tid >> 6;
  const int lane = tid & 63;
  const int quad = lane >> 4;
  const int l16 = lane & 15;
  const int blk = blockIdx.x;
  unsigned bi = 0;

  // ======== prologue: weight conversion + init ========
  {
    const int gtid = blk * 256 + tid;
#pragma unroll
    for (int rep = 0; rep < 2; ++rep) {
      int t4 = gtid + rep * 131072;  // 0..262143 groups of 4 floats
      const float* src;
      ushort_t* dst;
      if (t4 < 196608) {  // Wcat2: packed row p -> gate-interleaved
        int prow = t4 >> 7;
        int kk = (t4 & 127) * 4;
        int group = prow / 48;
        int within = prow % 48;
        int gate = within >> 4;
        int hh = group * 16 + (within & 15);
        src = (gate == 0 ? Wi : gate == 1 ? Wg : Wo) + (size_t)hh * HID + kk;
        dst = Wcat2 + (size_t)prow * HID + kk;
      } else {  // WoutB plain
        int t2 = t4 - 196608;
        int row = t2 >> 7;
        int kk = (t2 & 127) * 4;
        src = Wout + (size_t)row * HID + kk;
        dst = WoutB + (size_t)row * HID + kk;
      }
      float4 v = *(const float4*)src;
      union { unsigned short us[4]; uint2 u; } p;
      p.us[0] = f2bf(v.x); p.us[1] = f2bf(v.y);
      p.us[2] = f2bf(v.z); p.us[3] = f2bf(v.w);
      *(uint2*)dst = p.u;
    }
    // init: z=y, zb=bf16(y), out[:,0] = softmax(y)·Wfc + bfc (wave per row)
#pragma unroll
    for (int pass = 0; pass < 2; ++pass) {
      const int row = blk * 8 + pass * 4 + wave;
      const float4* y4 = (const float4*)(y + (size_t)row * HID);
      float4 v0 = y4[lane * 2];
      float4 v1 = y4[lane * 2 + 1];
      float zn[8] = {v0.x, v0.y, v0.z, v0.w, v1.x, v1.y, v1.z, v1.w};
      float4* z4 = (float4*)(z + (size_t)row * HID);
      z4[lane * 2] = v0;
      z4[lane * 2 + 1] = v1;
      union { unsigned short us[8]; uint4 v; } p;
#pragma unroll
      for (int i = 0; i < 8; ++i) p.us[i] = f2bf(zn[i]);
      *(uint4*)(zb + (size_t)row * HID + lane * 8) = p.v;

      const float4* w4 = (const float4*)Wfc;
      float4 w0 = w4[lane * 2], w1 = w4[lane * 2 + 1];
      float w[8] = {w0.x, w0.y, w0.z, w0.w, w1.x, w1.y, w1.z, w1.w};
      float m = zn[0];
#pragma unroll
      for (int i = 1; i < 8; ++i) m = fmaxf(m, zn[i]);
      m = wave_max(m);
      float s = 0.f, d = 0.f;
#pragma unroll
      for (int i = 0; i < 8; ++i) { float e = expf(zn[i] - m); s += e; d += e * w[i]; }
      s = wave_sum(s);
      d = wave_sum(d);
      if (lane == 0) out[(size_t)row * T_STEPS] = d / s + bfc[0];
    }
  }
  grid_barrier(cnt, ++bi * GRID);

  // ======== 19 Euler steps ========
  for (int t = 0; t < NSTEP; ++t) {
    // ---- phase A: dh = act(zb @ Wcat2^T), one 128x96 tile per block ----
    {
      ushort_t* As = (ushort_t*)smem;            // 128*32 ushorts
      ushort_t* Bs = (ushort_t*)(smem + 8192);   // 96*32 ushorts
      const int m0 = (blk & 31) * 128;
      const int n0 = (blk >> 5) * 96;
      const int wm = (wave & 1) * 64;
      const int wn = (wave >> 1) * 48;

      f32x4 acc[4][3] = {};
      const ushort_t* Ag = zb + (size_t)m0 * HID;
      const ushort_t* Bg = Wcat2 + (size_t)n0 * HID;

      for (int k0 = 0; k0 < HID; k0 += 32) {
        {
          const int c = wave * 64 + lane;
          load_lds16(Ag + (size_t)(c >> 2) * HID + k0 + (c & 3) * 8,
                     &As[(wave * 64) * 8]);
          const int c2 = c + 256;
          load_lds16(Ag + (size_t)(c2 >> 2) * HID + k0 + (c2 & 3) * 8,
                     &As[(256 + wave * 64) * 8]);
          load_lds16(Bg + (size_t)(c >> 2) * HID + k0 + (c & 3) * 8,
                     &Bs[(wave * 64) * 8]);
          if (wave < 2) {
            const int c3 = c + 256;
            load_lds16(Bg + (size_t)(c3 >> 2) * HID + k0 + (c3 & 3) * 8,
                       &Bs[(256 + wave * 64) * 8]);
          }
        }
        __syncthreads();

        bf16x8 af[4], bfr[3];
#pragma unroll
        for (int i = 0; i < 4; ++i)
          af[i] = *(const bf16x8*)&As[(wm + i * 16 + l16) * 32 + quad * 8];
#pragma unroll
        for (int j = 0; j < 3; ++j)
          bfr[j] = *(const bf16x8*)&Bs[(wn + j * 16 + l16) * 32 + quad * 8];
#pragma unroll
        for (int i = 0; i < 4; ++i)
#pragma unroll
          for (int j = 0; j < 3; ++j)
            acc[i][j] = __builtin_amdgcn_mfma_f32_16x16x32_bf16(af[i], bfr[j], acc[i][j], 0, 0, 0);
        __syncthreads();
      }

      // epilogue: C/D layout col=lane&15, row=quad*4+reg (m89-verified)
      const int hbase = (n0 + wn) / 3 + l16;
#pragma unroll
      for (int i = 0; i < 4; ++i) {
        const int row = m0 + wm + i * 16 + quad * 4;
#pragma unroll
        for (int r = 0; r < 4; ++r) {
          float vi = acc[i][0][r];
          float vg = acc[i][1][r];
          float vo = acc[i][2][r];
          float si = 1.f / (1.f + expf(-vi));
          float tg = tanhf(vg);
          float so = 1.f / (1.f + expf(-vo));
          dh[(size_t)(row + r) * HID + hbase] = f2bf(so * tanhf(si * tg));
        }
      }
    }
    grid_barrier(cnt, ++bi * GRID);

    // ---- phase B (blocks 0..127): 32 rows x 512 cols:
    //      C2 = dh@WoutB^T; softmax; z += dt*s; zb; out[:,t+1] readout ----
    if (blk < 128) {
      ushort_t* Bs = (ushort_t*)smem;              // 512*32 ushorts (32768 B)
      ushort_t* As = (ushort_t*)(smem + 32768);    // 32*32 ushorts (2048 B)
      float* redm = (float*)(smem + 34816);        // [4][32]
      float* redA = (float*)(smem + 35328);        // [4][32]
      float* redB = (float*)(smem + 35840);        // [4][32]

      const int m0 = blk * 32;
      const int wn = wave * 128;

      f32x4 acc[2][8] = {};

      for (int k0 = 0; k0 < HID; k0 += 32) {
#pragma unroll
        for (int r = 0; r < 8; ++r) {
          const int c = r * 256 + wave * 64 + lane;
          load_lds16(WoutB + (size_t)(c >> 2) * HID + k0 + (c & 3) * 8,
                     &Bs[(r * 256 + wave * 64) * 8]);
        }
        if (wave < 2) {
          const int c = wave * 64 + lane;
          load_lds16(dh + (size_t)(m0 + (c >> 2)) * HID + k0 + (c & 3) * 8,
                     &As[(wave * 64) * 8]);
        }
        __syncthreads();

        bf16x8 af0 = *(const bf16x8*)&As[(l16) * 32 + quad * 8];
        bf16x8 af1 = *(const bf16x8*)&As[(16 + l16) * 32 + quad * 8];
#pragma unroll
        for (int j = 0; j < 8; ++j) {
          bf16x8 bfr = *(const bf16x8*)&Bs[(wn + j * 16 + l16) * 32 + quad * 8];
          acc[0][j] = __builtin_amdgcn_mfma_f32_16x16x32_bf16(af0, bfr, acc[0][j], 0, 0, 0);
          acc[1][j] = __builtin_amdgcn_mfma_f32_16x16x32_bf16(af1, bfr, acc[1][j], 0, 0, 0);
        }
        __syncthreads();
      }

      const float dt = ts[t + 1] - ts[t];
      float bo[8], wf[8];
#pragma unroll
      for (int j = 0; j < 8; ++j) {
        bo[j] = bout[wn + j * 16 + l16];
        wf[j] = Wfc[wn + j * 16 + l16];
      }
      // logits in place
#pragma unroll
      for (int i = 0; i < 2; ++i)
#pragma unroll
        for (int j = 0; j < 8; ++j)
#pragma unroll
          for (int r = 0; r < 4; ++r) acc[i][j][r] += bo[j];

      // softmax #1 max: reduce over j then l16 (within quad); rows differ by quad
      float mrow[2][4];
#pragma unroll
      for (int i = 0; i < 2; ++i)
#pragma unroll
        for (int r = 0; r < 4; ++r) {
          float pm = acc[i][0][r];
#pragma unroll
          for (int j = 1; j < 8; ++j) pm = fmaxf(pm, acc[i][j][r]);
#pragma unroll
          for (int off = 1; off < 16; off <<= 1) pm = fmaxf(pm, __shfl_xor(pm, off));
          mrow[i][r] = pm;
        }
      if (l16 == 0) {
#pragma unroll
        for (int i = 0; i < 2; ++i)
#pragma unroll
          for (int r = 0; r < 4; ++r)
            redm[wave * 32 + i * 16 + quad * 4 + r] = mrow[i][r];
      }
      __syncthreads();
#pragma unroll
      for (int i = 0; i < 2; ++i)
#pragma unroll
        for (int r = 0; r < 4; ++r) {
          const int lrow = i * 16 + quad * 4 + r;
          float m = redm[lrow];
#pragma unroll
          for (int w = 1; w < 4; ++w) m = fmaxf(m, redm[w * 32 + lrow]);
          mrow[i][r] = m;
        }
      __syncthreads();

      // exp in place + sum
      float inv[2][4];
#pragma unroll
      for (int i = 0; i < 2; ++i)
#pragma unroll
        for (int r = 0; r < 4; ++r) {
          float ps = 0.f;
#pragma unroll
          for (int j = 0; j < 8; ++j) {
            acc[i][j][r] = expf(acc[i][j][r] - mrow[i][r]);
            ps += acc[i][j][r];
          }
#pragma unroll
          for (int off = 1; off < 16; off <<= 1) ps += __shfl_xor(ps, off);
          inv[i][r] = ps;  // partial; finalize via LDS
        }
      if (l16 == 0) {
#pragma unroll
        for (int i = 0; i < 2; ++i)
#pragma unroll
          for (int r = 0; r < 4; ++r)
            redm[wave * 32 + i * 16 + quad * 4 + r] = inv[i][r];
      }
      __syncthreads();
#pragma unroll
      for (int i = 0; i < 2; ++i)
#pragma unroll
        for (int r = 0; r < 4; ++r) {
          const int lrow = i * 16 + quad * 4 + r;
          float s = redm[lrow] + redm[32 + lrow] + redm[64 + lrow] + redm[96 + lrow];
          inv[i][r] = 1.f / s;
        }
      __syncthreads();

      // z update in place (acc becomes z_new)
#pragma unroll
      for (int i = 0; i < 2; ++i)
#pragma unroll
        for (int r = 0; r < 4; ++r) {
          const size_t base = (size_t)(m0 + i * 16 + quad * 4 + r) * HID;
#pragma unroll
          for (int j = 0; j < 8; ++j) {
            const size_t a = base + wn + j * 16 + l16;
            float v = z[a] + dt * acc[i][j][r] * inv[i][r];
            acc[i][j][r] = v;
            z[a] = v;
            zb[a] = f2bf(v);
          }
        }

      // softmax #2 over z_new + Wfc dot
      float mrow2[2][4];
#pragma unroll
      for (int i = 0; i < 2; ++i)
#pragma unroll
        for (int r = 0; r < 4; ++r) {
          float pm = acc[i][0][r];
#pragma unroll
          for (int j = 1; j < 8; ++j) pm = fmaxf(pm, acc[i][j][r]);
#pragma unroll
          for (int off = 1; off < 16; off <<= 1) pm = fmaxf(pm, __shfl_xor(pm, off));
          mrow2[i][r] = pm;
        }
      if (l16 == 0) {
#pragma unroll
        for (int i = 0; i < 2; ++i)
#pragma unroll
          for (int r = 0; r < 4; ++r)
            redm[wave * 32 + i * 16 + quad * 4 + r] = mrow2[i][r];
      }
      __syncthreads();
#pragma unroll
      for (int i = 0; i < 2; ++i)
#pragma unroll
        for (int r = 0; r < 4; ++r) {
          const int lrow = i * 16 + quad * 4 + r;
          float m = redm[lrow];
#pragma unroll
          for (int w = 1; w < 4; ++w) m = fmaxf(m, redm[w * 32 + lrow]);
          mrow2[i][r] = m;
        }
      __syncthreads();

#pragma unroll
      for (int i = 0; i < 2; ++i)
#pragma unroll
        for (int r = 0; r < 4; ++r) {
          float ps = 0.f, pd = 0.f;
#pragma unroll
          for (int j = 0; j < 8; ++j) {
            float e = expf(acc[i][j][r] - mrow2[i][r]);
            ps += e;
            pd += e * wf[j];
          }
#pragma unroll
          for (int off = 1; off < 16; off <<= 1) {
            ps += __shfl_xor(ps, off);
            pd += __shfl_xor(pd, off);
          }
          if (l16 == 0) {
            redA[wave * 32 + i * 16 + quad * 4 + r] = ps;
            redB[wave * 32 + i * 16 + quad * 4 + r] = pd;
          }
        }
      __syncthreads();
      if (tid < 32) {
        float s = redA[tid] + redA[32 + tid] + redA[64 + tid] + redA[96 + tid];
        float d = redB[tid] + redB[32 + tid] + redB[64 + tid] + redB[96 + tid];
        out[(size_t)(m0 + tid) * T_STEPS + t + 1] = d / s + bfc[0];
      }
    }
    grid_barrier(cnt, ++bi * GRID);
  }
}

extern "C" void kernel_launch(void* const* d_in, const int* in_sizes, int n_in,
                              void* d_out, int out_size, void* d_ws, size_t ws_size,
                              hipStream_t stream) {
  const float* y    = (const float*)d_in[0];
  const float* ts   = (const float*)d_in[1];
  const float* Wi   = (const float*)d_in[2];
  // d_in[3] = Wf: computed-but-unused in reference -> skipped
  const float* Wg   = (const float*)d_in[4];
  const float* Wo   = (const float*)d_in[5];
  const float* Wout = (const float*)d_in[6];
  const float* bout = (const float*)d_in[7];
  const float* Wfc  = (const float*)d_in[8];
  const float* bfc  = (const float*)d_in[9];
  float* out = (float*)d_out;

  char* ws = (char*)d_ws;
  float*    z     = (float*)(ws);                   // 4096*512*4  = 8388608
  ushort_t* zb    = (ushort_t*)(ws + 8388608);      // 4096*512*2  = 4194304
  ushort_t* dh    = (ushort_t*)(ws + 12582912);     // 4096*512*2  = 4194304
  ushort_t* Wcat2 = (ushort_t*)(ws + 16777216);     // 1536*512*2  = 1572864
  ushort_t* WoutB = (ushort_t*)(ws + 18350080);     // 512*512*2   = 524288
  unsigned* cnt   = (unsigned*)(ws + 18874368);     // barrier counter

  zero_kernel<<<1, 64, 0, stream>>>(cnt);
  fused_kernel<<<GRID, 256, 0, stream>>>(y, ts, Wi, Wg, Wo, Wout, bout, Wfc,
                                         bfc, out, z, zb, dh, Wcat2, WoutB, cnt);
}

// Round 4
// 1076.703 us; speedup vs baseline: 2.3198x; 2.3198x over previous
//
#include <hip/hip_runtime.h>
#include <cstdint>
#include <cstddef>

#define HID 512
#define BATCH 4096
#define T_STEPS 20

typedef unsigned short ushort_t;
typedef __attribute__((ext_vector_type(8))) __bf16 bf16x8;
typedef __attribute__((ext_vector_type(4))) float f32x4;

typedef __attribute__((address_space(1))) void gvoid;
typedef __attribute__((address_space(3))) void lvoid;

// fp32 -> bf16 round-to-nearest-even (finite inputs only)
__device__ __forceinline__ unsigned short f2bf(float f) {
  unsigned int u = __float_as_uint(f);
  u += 0x7FFFu + ((u >> 16) & 1u);
  return (unsigned short)(u >> 16);
}

__device__ __forceinline__ float wave_max(float v) {
#pragma unroll
  for (int off = 32; off > 0; off >>= 1) v = fmaxf(v, __shfl_xor(v, off));
  return v;
}
__device__ __forceinline__ float wave_sum(float v) {
#pragma unroll
  for (int off = 32; off > 0; off >>= 1) v += __shfl_xor(v, off);
  return v;
}

// async global->LDS, 16B per lane; lds base wave-uniform (HW adds lane*16)
__device__ __forceinline__ void load_lds16(const void* g, void* l) {
  __builtin_amdgcn_global_load_lds((gvoid*)g, (lvoid*)l, 16, 0, 0);
}

// ---------------------------------------------------------------------------
// Kernel A: dh[4096,512] = act( zb @ Wcat2^T ), Wcat2 gate-interleaved.
// 128x96 tile, BK=64, double-buffered LDS, chunk-major layout (conflict-free):
//   A slot16B = kc*128 + row (kc in [0,8), row in [0,128))
//   B slot16B = kc*96  + row (kc in [0,8), row in [0,96))
// ---------------------------------------------------------------------------
__global__ __launch_bounds__(256, 2) void gate_gemm_act(
    const ushort_t* __restrict__ A, const ushort_t* __restrict__ B,
    ushort_t* __restrict__ dh) {
  __shared__ ushort_t As[2][128 * 64];  // 2 x 16 KB
  __shared__ ushort_t Bs[2][96 * 64];   // 2 x 12 KB

  const int tid = threadIdx.x;
  const int wave = tid >> 6;
  const int lane = tid & 63;
  const int quad = lane >> 4;
  const int l16 = lane & 15;

  const int m0 = blockIdx.x * 128;
  const int n0 = blockIdx.y * 96;
  const int wm = (wave & 1) * 64;
  const int wn = (wave >> 1) * 48;

  const ushort_t* Ag = A + (size_t)m0 * HID;
  const ushort_t* Bg = B + (size_t)n0 * HID;

  f32x4 acc[4][3] = {};

  // stage BK=64 slab into buffer `buf` for K-offset k0
  auto stage = [&](int buf, int k0) {
#pragma unroll
    for (int q = 0; q < 4; ++q) {
      int g = wave + q * 4;         // A groups 0..15 (1024 chunks)
      int c = g * 64 + lane;
      int kc = c >> 7, row = c & 127;
      load_lds16(Ag + (size_t)row * HID + k0 + kc * 8, &As[buf][g * 512]);
    }
#pragma unroll
    for (int q = 0; q < 3; ++q) {
      int g = wave * 3 + q;         // B groups 0..11 (768 chunks)
      int c = g * 64 + lane;
      int kc = c / 96, row = c - 96 * kc;
      load_lds16(Bg + (size_t)row * HID + k0 + kc * 8, &Bs[buf][g * 512]);
    }
  };

  stage(0, 0);
  for (int it = 0; it < 8; ++it) {
    __syncthreads();                         // vmcnt(0): current buf ready
    if (it < 7) stage((it + 1) & 1, (it + 1) * 64);
    const ushort_t* Ab = As[it & 1];
    const ushort_t* Bb = Bs[it & 1];
#pragma unroll
    for (int s = 0; s < 2; ++s) {
      bf16x8 af[4], bfr[3];
#pragma unroll
      for (int i = 0; i < 4; ++i)
        af[i] = *(const bf16x8*)&Ab[((s * 4 + quad) * 128 + wm + i * 16 + l16) * 8];
#pragma unroll
      for (int j = 0; j < 3; ++j)
        bfr[j] = *(const bf16x8*)&Bb[((s * 4 + quad) * 96 + wn + j * 16 + l16) * 8];
#pragma unroll
      for (int i = 0; i < 4; ++i)
#pragma unroll
        for (int j = 0; j < 3; ++j)
          acc[i][j] = __builtin_amdgcn_mfma_f32_16x16x32_bf16(af[i], bfr[j], acc[i][j], 0, 0, 0);
    }
  }

  // epilogue: C/D layout col=lane&15, row=quad*4+reg (m89-verified)
  const int hbase = (n0 + wn) / 3 + l16;  // n0+wn multiple of 48
#pragma unroll
  for (int i = 0; i < 4; ++i) {
    const int row = m0 + wm + i * 16 + quad * 4;
#pragma unroll
    for (int r = 0; r < 4; ++r) {
      float vi = acc[i][0][r];
      float vg = acc[i][1][r];
      float vo = acc[i][2][r];
      float si = 1.f / (1.f + expf(-vi));
      float tg = tanhf(vg);
      float so = 1.f / (1.f + expf(-vo));
      dh[(size_t)(row + r) * HID + hbase] = f2bf(so * tanhf(si * tg));
    }
  }
}

// ---------------------------------------------------------------------------
// Kernel B: 32 rows x 512 cols per block, 128 blocks x 512 threads (8 waves,
// wave w owns cols w*64..w*64+63). A (32x512, 32 KB) staged to LDS ONCE
// (chunk-major, conflict-free); B loaded DIRECTLY global->VGPR (no intra-block
// reuse across waves -> LDS staging would be pure overhead). No barriers in
// the K-loop. Then: softmax(C2+bout), z += dt*s, zb=bf16(z), readout.
// ---------------------------------------------------------------------------
__global__ __launch_bounds__(512, 2) void gemm2_update(
    const ushort_t* __restrict__ dhp, const ushort_t* __restrict__ WoutB,
    const float* __restrict__ bout, float* __restrict__ z,
    ushort_t* __restrict__ zb, const float* __restrict__ Wfc,
    const float* __restrict__ bfc, const float* __restrict__ ts,
    float* __restrict__ out, int t) {
  __shared__ ushort_t As[32 * 512];   // 32 KB, slot16B = kc*32 + row
  __shared__ float redm[8 * 32];
  __shared__ float redA[8 * 32];
  __shared__ float redB[8 * 32];

  const int tid = threadIdx.x;
  const int wave = tid >> 6;
  const int lane = tid & 63;
  const int quad = lane >> 4;
  const int l16 = lane & 15;

  const int m0 = blockIdx.x * 32;
  const int wn = wave * 64;

  // stage full A tile (2048 chunks, 32 groups; wave issues 4)
#pragma unroll
  for (int q = 0; q < 4; ++q) {
    int g = wave * 4 + q;
    int c = g * 64 + lane;
    int kc = c >> 5, row = c & 31;
    load_lds16(dhp + (size_t)(m0 + row) * HID + kc * 8, &As[g * 512]);
  }
  __syncthreads();

  f32x4 acc[2][4] = {};
#pragma unroll
  for (int s = 0; s < 16; ++s) {
    bf16x8 bfr[4];
#pragma unroll
    for (int j = 0; j < 4; ++j)
      bfr[j] = *(const bf16x8*)(WoutB + (size_t)(wn + j * 16 + l16) * HID + s * 32 + quad * 8);
    bf16x8 af0 = *(const bf16x8*)&As[((s * 4 + quad) * 32 + l16) * 8];
    bf16x8 af1 = *(const bf16x8*)&As[((s * 4 + quad) * 32 + 16 + l16) * 8];
#pragma unroll
    for (int j = 0; j < 4; ++j) {
      acc[0][j] = __builtin_amdgcn_mfma_f32_16x16x32_bf16(af0, bfr[j], acc[0][j], 0, 0, 0);
      acc[1][j] = __builtin_amdgcn_mfma_f32_16x16x32_bf16(af1, bfr[j], acc[1][j], 0, 0, 0);
    }
  }

  const float dt = ts[t + 1] - ts[t];
  float bo[4], wf[4];
#pragma unroll
  for (int j = 0; j < 4; ++j) {
    bo[j] = bout[wn + j * 16 + l16];
    wf[j] = Wfc[wn + j * 16 + l16];
  }
#pragma unroll
  for (int i = 0; i < 2; ++i)
#pragma unroll
    for (int j = 0; j < 4; ++j)
#pragma unroll
      for (int r = 0; r < 4; ++r) acc[i][j][r] += bo[j];

  // ---- softmax #1 max ----
  float mrow[2][4];
#pragma unroll
  for (int i = 0; i < 2; ++i)
#pragma unroll
    for (int r = 0; r < 4; ++r) {
      float pm = fmaxf(fmaxf(acc[i][0][r], acc[i][1][r]), fmaxf(acc[i][2][r], acc[i][3][r]));
#pragma unroll
      for (int off = 1; off < 16; off <<= 1) pm = fmaxf(pm, __shfl_xor(pm, off));
      mrow[i][r] = pm;
    }
  if (l16 == 0) {
#pragma unroll
    for (int i = 0; i < 2; ++i)
#pragma unroll
      for (int r = 0; r < 4; ++r)
        redm[wave * 32 + i * 16 + quad * 4 + r] = mrow[i][r];
  }
  __syncthreads();
#pragma unroll
  for (int i = 0; i < 2; ++i)
#pragma unroll
    for (int r = 0; r < 4; ++r) {
      const int lrow = i * 16 + quad * 4 + r;
      float m = redm[lrow];
#pragma unroll
      for (int w = 1; w < 8; ++w) m = fmaxf(m, redm[w * 32 + lrow]);
      mrow[i][r] = m;
    }
  __syncthreads();

  // ---- exp + sum ----
  float inv[2][4];
#pragma unroll
  for (int i = 0; i < 2; ++i)
#pragma unroll
    for (int r = 0; r < 4; ++r) {
      float ps = 0.f;
#pragma unroll
      for (int j = 0; j < 4; ++j) {
        acc[i][j][r] = expf(acc[i][j][r] - mrow[i][r]);
        ps += acc[i][j][r];
      }
#pragma unroll
      for (int off = 1; off < 16; off <<= 1) ps += __shfl_xor(ps, off);
      inv[i][r] = ps;
    }
  if (l16 == 0) {
#pragma unroll
    for (int i = 0; i < 2; ++i)
#pragma unroll
      for (int r = 0; r < 4; ++r)
        redm[wave * 32 + i * 16 + quad * 4 + r] = inv[i][r];
  }
  __syncthreads();
#pragma unroll
  for (int i = 0; i < 2; ++i)
#pragma unroll
    for (int r = 0; r < 4; ++r) {
      const int lrow = i * 16 + quad * 4 + r;
      float s = 0.f;
#pragma unroll
      for (int w = 0; w < 8; ++w) s += redm[w * 32 + lrow];
      inv[i][r] = 1.f / s;
    }
  __syncthreads();

  // ---- z update (acc becomes z_new) ----
#pragma unroll
  for (int i = 0; i < 2; ++i)
#pragma unroll
    for (int r = 0; r < 4; ++r) {
      const size_t base = (size_t)(m0 + i * 16 + quad * 4 + r) * HID;
#pragma unroll
      for (int j = 0; j < 4; ++j) {
        const size_t a = base + wn + j * 16 + l16;
        float v = z[a] + dt * acc[i][j][r] * inv[i][r];
        acc[i][j][r] = v;
        z[a] = v;
        zb[a] = f2bf(v);
      }
    }

  // ---- softmax #2 + readout dot ----
  float mrow2[2][4];
#pragma unroll
  for (int i = 0; i < 2; ++i)
#pragma unroll
    for (int r = 0; r < 4; ++r) {
      float pm = fmaxf(fmaxf(acc[i][0][r], acc[i][1][r]), fmaxf(acc[i][2][r], acc[i][3][r]));
#pragma unroll
      for (int off = 1; off < 16; off <<= 1) pm = fmaxf(pm, __shfl_xor(pm, off));
      mrow2[i][r] = pm;
    }
  if (l16 == 0) {
#pragma unroll
    for (int i = 0; i < 2; ++i)
#pragma unroll
      for (int r = 0; r < 4; ++r)
        redm[wave * 32 + i * 16 + quad * 4 + r] = mrow2[i][r];
  }
  __syncthreads();
#pragma unroll
  for (int i = 0; i < 2; ++i)
#pragma unroll
    for (int r = 0; r < 4; ++r) {
      const int lrow = i * 16 + quad * 4 + r;
      float m = redm[lrow];
#pragma unroll
      for (int w = 1; w < 8; ++w) m = fmaxf(m, redm[w * 32 + lrow]);
      mrow2[i][r] = m;
    }
  __syncthreads();

#pragma unroll
  for (int i = 0; i < 2; ++i)
#pragma unroll
    for (int r = 0; r < 4; ++r) {
      float ps = 0.f, pd = 0.f;
#pragma unroll
      for (int j = 0; j < 4; ++j) {
        float e = expf(acc[i][j][r] - mrow2[i][r]);
        ps += e;
        pd += e * wf[j];
      }
#pragma unroll
      for (int off = 1; off < 16; off <<= 1) {
        ps += __shfl_xor(ps, off);
        pd += __shfl_xor(pd, off);
      }
      if (l16 == 0) {
        redA[wave * 32 + i * 16 + quad * 4 + r] = ps;
        redB[wave * 32 + i * 16 + quad * 4 + r] = pd;
      }
    }
  __syncthreads();
  if (tid < 32) {
    float s = 0.f, d = 0.f;
#pragma unroll
    for (int w = 0; w < 8; ++w) { s += redA[w * 32 + tid]; d += redB[w * 32 + tid]; }
    out[(size_t)(m0 + tid) * T_STEPS + t + 1] = d / s + bfc[0];
  }
}

// ---------------------------------------------------------------------------
// weights fp32 -> bf16. Wcat2 gate-interleaved [1536,512]; WoutB plain.
// ---------------------------------------------------------------------------
__global__ __launch_bounds__(256) void convw_kernel(
    const float* __restrict__ Wi, const float* __restrict__ Wg,
    const float* __restrict__ Wo, const float* __restrict__ Wout,
    ushort_t* __restrict__ Wcat2, ushort_t* __restrict__ WoutB) {
  const int t = blockIdx.x * 256 + threadIdx.x;  // 1024 x 256 = 262144
  const float* src;
  ushort_t* dst;
  if (t < 196608) {
    int prow = t >> 7;
    int kk = (t & 127) * 4;
    int group = prow / 48;
    int within = prow % 48;
    int gate = within >> 4;
    int hh = group * 16 + (within & 15);
    src = (gate == 0 ? Wi : gate == 1 ? Wg : Wo) + (size_t)hh * HID + kk;
    dst = Wcat2 + (size_t)prow * HID + kk;
  } else {
    int t2 = t - 196608;
    int row = t2 >> 7;
    int kk = (t2 & 127) * 4;
    src = Wout + (size_t)row * HID + kk;
    dst = WoutB + (size_t)row * HID + kk;
  }
  float4 v = *(const float4*)src;
  union { unsigned short us[4]; uint2 u; } p;
  p.us[0] = f2bf(v.x); p.us[1] = f2bf(v.y); p.us[2] = f2bf(v.z); p.us[3] = f2bf(v.w);
  *(uint2*)dst = p.u;
}

// z = y ; zb = bf16(y) ; out[:,0] = softmax(y)·Wfc + bfc (one wave per row)
__global__ __launch_bounds__(256) void init_kernel(
    const float* __restrict__ y, float* __restrict__ z, ushort_t* __restrict__ zb,
    const float* __restrict__ Wfc, const float* __restrict__ bfc,
    float* __restrict__ out) {
  const int wave = threadIdx.x >> 6;
  const int lane = threadIdx.x & 63;
  const int row = blockIdx.x * 4 + wave;
  const float4* y4 = (const float4*)(y + (size_t)row * HID);
  float4 v0 = y4[lane * 2];
  float4 v1 = y4[lane * 2 + 1];
  float zn[8] = {v0.x, v0.y, v0.z, v0.w, v1.x, v1.y, v1.z, v1.w};
  float4* z4 = (float4*)(z + (size_t)row * HID);
  z4[lane * 2] = v0;
  z4[lane * 2 + 1] = v1;
  union { unsigned short us[8]; uint4 v; } p;
#pragma unroll
  for (int i = 0; i < 8; ++i) p.us[i] = f2bf(zn[i]);
  *(uint4*)(zb + (size_t)row * HID + lane * 8) = p.v;

  const float4* w4 = (const float4*)Wfc;
  float4 w0 = w4[lane * 2], w1 = w4[lane * 2 + 1];
  float w[8] = {w0.x, w0.y, w0.z, w0.w, w1.x, w1.y, w1.z, w1.w};
  float m = zn[0];
#pragma unroll
  for (int i = 1; i < 8; ++i) m = fmaxf(m, zn[i]);
  m = wave_max(m);
  float s = 0.f, d = 0.f;
#pragma unroll
  for (int i = 0; i < 8; ++i) { float e = expf(zn[i] - m); s += e; d += e * w[i]; }
  s = wave_sum(s);
  d = wave_sum(d);
  if (lane == 0) out[(size_t)row * T_STEPS] = d / s + bfc[0];
}

extern "C" void kernel_launch(void* const* d_in, const int* in_sizes, int n_in,
                              void* d_out, int out_size, void* d_ws, size_t ws_size,
                              hipStream_t stream) {
  const float* y    = (const float*)d_in[0];
  const float* ts   = (const float*)d_in[1];
  const float* Wi   = (const float*)d_in[2];
  // d_in[3] = Wf: computed-but-unused in reference -> skipped
  const float* Wg   = (const float*)d_in[4];
  const float* Wo   = (const float*)d_in[5];
  const float* Wout = (const float*)d_in[6];
  const float* bout = (const float*)d_in[7];
  const float* Wfc  = (const float*)d_in[8];
  const float* bfc  = (const float*)d_in[9];
  float* out = (float*)d_out;

  char* ws = (char*)d_ws;
  float*    z     = (float*)(ws);                   // 4096*512*4  = 8388608
  ushort_t* zb    = (ushort_t*)(ws + 8388608);      // 4096*512*2  = 4194304
  ushort_t* dh    = (ushort_t*)(ws + 12582912);     // 4096*512*2  = 4194304
  ushort_t* Wcat2 = (ushort_t*)(ws + 16777216);     // 1536*512*2  = 1572864
  ushort_t* WoutB = (ushort_t*)(ws + 18350080);     // 512*512*2   = 524288

  convw_kernel<<<1024, 256, 0, stream>>>(Wi, Wg, Wo, Wout, Wcat2, WoutB);
  init_kernel<<<BATCH / 4, 256, 0, stream>>>(y, z, zb, Wfc, bfc, out);

  for (int t = 0; t < T_STEPS - 1; ++t) {
    gate_gemm_act<<<dim3(BATCH / 128, 1536 / 96), 256, 0, stream>>>(zb, Wcat2, dh);
    gemm2_update<<<128, 512, 0, stream>>>(dh, WoutB, bout, z, zb, Wfc, bfc, ts, out, t);
  }
}